// Round 25
// baseline (65.896 us; speedup 1.0000x reference)
//
#include <hip/hip_runtime.h>
#include <math.h>

typedef float f32x4 __attribute__((ext_vector_type(4)));
typedef int   i32x4 __attribute__((ext_vector_type(4)));
typedef signed char i8x8 __attribute__((ext_vector_type(8)));
typedef __fp16 h16x2 __attribute__((ext_vector_type(2)));

#define NROWS 8192
#define NCOLS 512
#define BHALF 4096
#define NT    64       // super-rows: 8192 / 128
#define NBLK  2080     // NT*(NT+1)/2 super-tiles; 2080 = 8*260
#define CSPART 256     // colsum partial blocks
#define QS    24.0f    // int8 quantization scale (clip at ~5.3 sigma)
#define INV_S2 (1.0f / (24.0f * 24.0f))

// ---------- fused conversion + i8-FRAGMENT repack + row-sqi + partials ----------
// 256 blocks x 256 threads; block covers 32 rows (2 rowgrps of 16).
// bfrag (int8): chunk (rowgrp g, kslot sl, lane lr) at byte g*8192+sl*256+lr*16.
// Per-row INT sumsq (sqi) for the exact l2; per-BLOCK fp32 sumsq partial
// (sqpart, double) for the bandwidth. Deterministic: fixed-order, no atomics.
__global__ void k_conv(const float* __restrict__ src, const float* __restrict__ tgt,
                       signed char* __restrict__ bfrag, int* __restrict__ sqi,
                       double* __restrict__ sqpart, float* __restrict__ cspart) {
    __shared__ signed char ldsc[32][528];   // 512 + 16B pad
    __shared__ float colp[4][NCOLS];
    __shared__ double dred[4];
    int t = threadIdx.x, w = t >> 6, l = t & 63;
    int r0 = blockIdx.x * 32;
    float c0x=0.f,c0y=0.f,c0z=0.f,c0w=0.f, c1x=0.f,c1y=0.f,c1z=0.f,c1w=0.f;
    double facc = 0.0;
    #pragma unroll
    for (int r = 0; r < 8; ++r) {
        int row = r0 + w * 8 + r;
        const float* base = (row < BHALF) ? (src + (size_t)row * NCOLS)
                                          : (tgt + (size_t)(row - BHALF) * NCOLS);
        float4 a = ((const float4*)base)[2 * l];
        float4 b = ((const float4*)base)[2 * l + 1];
        int q0 = (int)rintf(fminf(fmaxf(a.x * QS, -127.f), 127.f));
        int q1 = (int)rintf(fminf(fmaxf(a.y * QS, -127.f), 127.f));
        int q2 = (int)rintf(fminf(fmaxf(a.z * QS, -127.f), 127.f));
        int q3 = (int)rintf(fminf(fmaxf(a.w * QS, -127.f), 127.f));
        int q4 = (int)rintf(fminf(fmaxf(b.x * QS, -127.f), 127.f));
        int q5 = (int)rintf(fminf(fmaxf(b.y * QS, -127.f), 127.f));
        int q6 = (int)rintf(fminf(fmaxf(b.z * QS, -127.f), 127.f));
        int q7 = (int)rintf(fminf(fmaxf(b.w * QS, -127.f), 127.f));
        i8x8 v8;
        v8[0]=(signed char)q0; v8[1]=(signed char)q1; v8[2]=(signed char)q2; v8[3]=(signed char)q3;
        v8[4]=(signed char)q4; v8[5]=(signed char)q5; v8[6]=(signed char)q6; v8[7]=(signed char)q7;
        *(i8x8*)&ldsc[w * 8 + r][l * 8] = v8;
        float s = a.x*a.x + a.y*a.y + a.z*a.z + a.w*a.w
                + b.x*b.x + b.y*b.y + b.z*b.z + b.w*b.w;
        facc += (double)s;
        int si = q0*q0 + q1*q1 + q2*q2 + q3*q3 + q4*q4 + q5*q5 + q6*q6 + q7*q7;
        #pragma unroll
        for (int o = 32; o > 0; o >>= 1) si += __shfl_down(si, o);
        if (l == 0) sqi[row] = si;
        c0x += a.x; c0y += a.y; c0z += a.z; c0w += a.w;
        c1x += b.x; c1y += b.y; c1z += b.z; c1w += b.w;
    }
    #pragma unroll
    for (int o = 32; o > 0; o >>= 1) facc += __shfl_down(facc, o);
    if (l == 0) dred[w] = facc;
    colp[w][l*8+0] = c0x; colp[w][l*8+1] = c0y; colp[w][l*8+2] = c0z; colp[w][l*8+3] = c0w;
    colp[w][l*8+4] = c1x; colp[w][l*8+5] = c1y; colp[w][l*8+6] = c1z; colp[w][l*8+7] = c1w;
    __syncthreads();
    if (t == 0) sqpart[blockIdx.x] = (dred[0] + dred[1]) + (dred[2] + dred[3]);
    float s0 = colp[0][t] + colp[1][t] + colp[2][t] + colp[3][t];
    float s1 = colp[0][t+256] + colp[1][t+256] + colp[2][t+256] + colp[3][t+256];
    cspart[(size_t)blockIdx.x * NCOLS + t]       = s0;
    cspart[(size_t)blockIdx.x * NCOLS + t + 256] = s1;
    // repack: 2 rowgrps x 32 kslots x 16 lanes = 1024 chunks of 16B, 4/thread
    int rg0 = blockIdx.x * 2;
    #pragma unroll
    for (int c4 = 0; c4 < 4; ++c4) {
        int c = c4 * 256 + t;
        int g = c >> 9, sl = (c >> 4) & 31, lrr = c & 15;
        i32x4 v = *(const i32x4*)&ldsc[g * 16 + lrr][sl * 16];
        *(i32x4*)(bfrag + (size_t)(rg0 + g) * 8192 + sl * 256 + lrr * 16) = v;
    }
}

// ---------- coalesced column reduction: 8 blocks x 256 threads ----------
__global__ void k_red(const float* __restrict__ cspart, double* __restrict__ colsq) {
    __shared__ double lred[4][64];
    int b = blockIdx.x, t = threadIdx.x;
    int c = b * 64 + (t & 63), q = t >> 6;
    double a = 0.0;
    #pragma unroll 4
    for (int p = q * 64; p < q * 64 + 64; ++p)
        a += (double)cspart[(size_t)p * NCOLS + c];
    lred[q][t & 63] = a;
    __syncthreads();
    if (t < 64) {
        double s = (lred[0][t] + lred[1][t]) + (lred[2][t] + lred[3][t]);
        colsq[b * 64 + t] = s * s;
    }
}

// bandwidth from analytic sum(l2) = 2n*T - 2*||colsum||^2 ; store log2(e)/bw_k.
__global__ void k_bw(const double* __restrict__ sqpart, const double* __restrict__ colsq,
                     float* __restrict__ cvals) {
    __shared__ double red[512];
    int t = threadIdx.x;
    red[t] = (t < CSPART) ? sqpart[t] : 0.0;
    __syncthreads();
    for (int o = 256; o > 0; o >>= 1) { if (t < o) red[t] += red[t + o]; __syncthreads(); }
    double sT = red[0];
    __syncthreads();
    red[t] = colsq[t]; __syncthreads();
    for (int o = 256; o > 0; o >>= 1) { if (t < o) red[t] += red[t + o]; __syncthreads(); }
    if (t == 0) {
        double G = red[0];
        double sum_l2 = 2.0 * (double)NROWS * sT - 2.0 * G;
        double denom = (double)NROWS * (double)NROWS - (double)NROWS;
        double bw = sum_l2 / denom / 4.0;   // KERNEL_MUL^(KERNEL_NUM/2) = 4
        const double L2E = 1.4426950408889634;
        double b = bw;
        #pragma unroll
        for (int k = 0; k < 5; ++k) { cvals[k] = (float)(L2E / b); b *= 2.0; }
    }
}

// ---------- main fused MMD kernel: 4-wave i8 fragment streaming ----------
// R24 structure (256-thr, 2x2 super-tile waves, dup-diagonal, single fragment
// set, saddr bases, closed-form sqrt decode, RNE packed-fp16 epilogue).
// NEW: one raw s_barrier per kt to ALIGN the 4 waves' kt-windows. Mechanism:
// the supertile has 2-way panel sharing (waves {0,1}/{2,3} share A, {0,2}/
// {1,3} share B) but drifting waves thrash L1 (128KB set) and each pulls its
// own copy from L2 -- measured plateau fits an effective ~19 B/cyc/CU L2
// return rate exactly. Aligned kt-windows shrink the live set to 4x4KB=16KB
// <= 32KB L1 -> second reader hits L1 -> L2 traffic halves. Raw s_barrier
// only (NOT __syncthreads: its vmcnt-drain would serialize loads, the R7
// stall); correctness-free -- no inter-wave data flow, uniform control flow.
__global__ __launch_bounds__(256, 4)
void k_mmd(const signed char* __restrict__ bfrag, const int* __restrict__ sqi,
           const float* __restrict__ cvals, double* __restrict__ psum) {
    __shared__ float wred[4];

    // T1: XCD-aware bijective swizzle (NBLK = 8*260), closed-form decode
    int bid = blockIdx.x;
    int swz = (bid & 7) * (NBLK / 8) + (bid >> 3);
    int v = NBLK - 1 - swz;
    int k = (int)((sqrtf(8.f * (float)v + 1.f) - 1.f) * 0.5f);
    while ((k + 1) * (k + 2) / 2 <= v) ++k;
    while (k * (k + 1) / 2 > v) --k;
    int I = NT - 1 - k;
    int J = NT - 1 - (v - k * (k + 1) / 2);

    const int t  = threadIdx.x;
    const int w  = t >> 6;       // wave 0..3
    const int l  = t & 63;
    const int lr = l & 15;
    const int lk = l >> 4;

    // wave -> tile assignment within the 2x2 super-tile (R16-proven)
    const bool dsup = (I == J);
    int da, db;
    if (dsup) { da = (w == 2) ? 1 : 0; db = (w == 0) ? 0 : 1; }
    else      { da = w >> 1;           db = w & 1; }
    const int i_t = 2 * I + da, j_t = 2 * J + db;
    const int rowA0 = i_t * 64, rowB0 = j_t * 64;

    // wave-uniform SGPR panel bases + one 32-bit per-lane byte voffset
    const int i_u = __builtin_amdgcn_readfirstlane(i_t);
    const int j_u = __builtin_amdgcn_readfirstlane(j_t);
    const signed char* bA = bfrag + (size_t)i_u * 32768;
    const signed char* bB = bfrag + (size_t)j_u * 32768;
    const int voff = lk * 256 + lr * 16;   // bytes

    i32x4 acc[4][4] = {};
    #pragma unroll
    for (int kt = 0; kt < 8; ++kt) {
        __builtin_amdgcn_s_barrier();   // align kt-windows (scheduling only)
        i32x4 af[4], bf[4];
        #pragma unroll
        for (int m = 0; m < 4; ++m)
            af[m] = *(const i32x4*)(bA + m * 8192 + kt * 1024 + voff);
        #pragma unroll
        for (int n = 0; n < 4; ++n)
            bf[n] = *(const i32x4*)(bB + n * 8192 + kt * 1024 + voff);
        #pragma unroll
        for (int m = 0; m < 4; ++m)
            #pragma unroll
            for (int n = 0; n < 4; ++n)
                acc[m][n] = __builtin_amdgcn_mfma_i32_16x16x64_i8(
                    af[m], bf[n], acc[m][n], 0, 0, 0);
    }

    // ---------- epilogue ----------
    i32x4 sqa[4];
    #pragma unroll
    for (int m = 0; m < 4; ++m)
        sqa[m] = *(const i32x4*)&sqi[rowA0 + m * 16 + lk * 4];
    int sqb[4];
    #pragma unroll
    for (int n = 0; n < 4; ++n)
        sqb[n] = sqi[rowB0 + n * 16 + lr];
    const float c4i = cvals[4] * INV_S2;   // fold 1/s^2 into the exp constant
    const float c2  = 2.f * c4i;
    // hoisted scaled norms: arg = 2d*c4i - (sqa+sqb)*c4i  (= -l2*c4i)
    f32x4 sqaf[4];
    #pragma unroll
    for (int m = 0; m < 4; ++m)
        #pragma unroll
        for (int r = 0; r < 4; ++r)
            sqaf[m][r] = c4i * (float)sqa[m][r];
    float sqbf[4];
    #pragma unroll
    for (int n = 0; n < 4; ++n)
        sqbf[n] = c4i * (float)sqb[n];

    const bool elem = dsup && ((w & 1) == 0);        // elementwise-diag tiles
    const float wb  = dsup ? 1.f : 2.f;              // pair weight (dup tiles sum to 2)
    const float sgn = ((rowA0 < BHALF) == (rowB0 < BHALF)) ? 1.f : -1.f;
    float local = 0.f;
    if (elem) {
        // exact scalar fp32 path with per-element weights (diag supers only)
        #pragma unroll
        for (int m = 0; m < 4; ++m)
            #pragma unroll
            for (int n = 0; n < 4; ++n)
                #pragma unroll
                for (int r = 0; r < 4; ++r) {
                    float x  = __builtin_amdgcn_exp2f(
                        fmaf((float)acc[m][n][r], c2, -(sqaf[m][r] + sqbf[n])));
                    float x2 = x * x;
                    float x4 = x2 * x2;
                    float x8 = x4 * x4;
                    float e  = fmaf(x8, x8, x8) + ((x + x2) + x4);
                    int gi = rowA0 + m * 16 + lk * 4 + r;
                    int gj = rowB0 + n * 16 + lr;
                    float wgt = (gj > gi) ? 2.f : ((gj == gi) ? 1.f : 0.f);
                    local += wgt * e;
                }
    } else {
        // packed-fp16 path: RNE converts (unbiased), pk square-chain,
        // fp32 accumulation via v_dot2_f32_f16 (guarded).
        const h16x2 ones = {(__fp16)1.f, (__fp16)1.f};
        #pragma unroll
        for (int m = 0; m < 4; ++m)
            #pragma unroll
            for (int n = 0; n < 4; ++n)
                #pragma unroll
                for (int rp = 0; rp < 2; ++rp) {
                    float x0 = __builtin_amdgcn_exp2f(
                        fmaf((float)acc[m][n][2*rp],     c2, -(sqaf[m][2*rp]     + sqbf[n])));
                    float x1 = __builtin_amdgcn_exp2f(
                        fmaf((float)acc[m][n][2*rp + 1], c2, -(sqaf[m][2*rp + 1] + sqbf[n])));
                    h16x2 x  = {(__fp16)x0, (__fp16)x1};   // RNE converts
                    h16x2 x2 = x * x;
                    h16x2 x4 = x2 * x2;
                    h16x2 x8 = x4 * x4;
                    h16x2 e2 = ((x + x2) + (x4 + x8)) + x8 * x8;
#if __has_builtin(__builtin_amdgcn_fdot2)
                    local = __builtin_amdgcn_fdot2(e2, ones, local, false);
#else
                    local += (float)e2[0] + (float)e2[1];
#endif
                }
        local *= wb * sgn;   // dsup non-elem tiles: wb=1, sgn=+1
    }

    #pragma unroll
    for (int o = 32; o > 0; o >>= 1) local += __shfl_down(local, o);
    if (l == 0) wred[w] = local;
    __syncthreads();
    if (t == 0) {
        psum[blockIdx.x] = (double)((wred[0] + wred[1]) + (wred[2] + wred[3]));
    }
}

// fixed-order final reduction over NBLK partials -> loss
__global__ void k_final(const double* __restrict__ psum, float* __restrict__ out) {
    __shared__ double red[512];
    int t = threadIdx.x;
    double a = 0.0;
    #pragma unroll
    for (int i = t; i < NBLK; i += 512) a += psum[i];
    red[t] = a; __syncthreads();
    for (int o = 256; o > 0; o >>= 1) { if (t < o) red[t] += red[t + o]; __syncthreads(); }
    if (t == 0) out[0] = (float)(red[0] * (1.0 / ((double)BHALF * (double)BHALF)));
}

// ---------- launch ----------
extern "C" void kernel_launch(void* const* d_in, const int* in_sizes, int n_in,
                              void* d_out, int out_size, void* d_ws, size_t ws_size,
                              hipStream_t stream) {
    (void)in_sizes; (void)n_in; (void)out_size; (void)ws_size;
    const float* src = (const float*)d_in[0];
    const float* tgt = (const float*)d_in[1];
    float* out = (float*)d_out;
    char* ws = (char*)d_ws;
    // layout (16B-aligned; every consumed word is rewritten each call):
    signed char* bfrag = (signed char*)(ws);          // 4194304 B
    int*    sqi    = (int*)   (ws + 4194304);         // 32768 B
    float*  cspart = (float*) (ws + 4227072);         // 524288 B
    float*  cvals  = (float*) (ws + 4751360);         // 20 B (pad 32)
    double* colsq  = (double*)(ws + 4751392);         // 4096 B
    double* sqpart = (double*)(ws + 4755488);         // 2048 B
    double* psum   = (double*)(ws + 4757536);         // 2080*8 = 16640 B

    k_conv  <<<CSPART, 256, 0, stream>>>(src, tgt, bfrag, sqi, sqpart, cspart);
    k_red   <<<8, 256, 0, stream>>>(cspart, colsq);
    k_bw    <<<1, 512, 0, stream>>>(sqpart, colsq, cvals);
    k_mmd   <<<NBLK, 256, 0, stream>>>(bfrag, sqi, cvals, psum);
    k_final <<<1, 512, 0, stream>>>(psum, out);
}

// Round 26
// 54.007 us; speedup vs baseline: 1.2201x; 1.2201x over previous
//
#include <hip/hip_runtime.h>
#include <math.h>

typedef float f32x4 __attribute__((ext_vector_type(4)));
typedef int   i32x4 __attribute__((ext_vector_type(4)));
typedef signed char i8x8 __attribute__((ext_vector_type(8)));
typedef __fp16 h16x2 __attribute__((ext_vector_type(2)));

#define NROWS 8192
#define NCOLS 512
#define BHALF 4096
#define NT    64       // super-rows: 8192 / 128
#define NBLK  2080     // NT*(NT+1)/2 super-tiles; 2080 = 8*260
#define CSPART 256     // colsum partial blocks
#define QS    24.0f    // int8 quantization scale (clip at ~5.3 sigma)
#define INV_S2 (1.0f / (24.0f * 24.0f))

typedef __attribute__((address_space(1))) const unsigned int guint;
typedef __attribute__((address_space(3))) unsigned int luint;

// ---------- fused conversion (ROW-MAJOR i8) + row-sqi + partials ----------
// 256 blocks x 256 threads; block covers 32 rows. bfall is plain row-major
// int8 (8192 x 512) -- the LDS-staged GEMM needs no fragment repack, so the
// transpose LDS pass is gone: each thread quantizes 8 values and stores 8 B.
// Per-row INT sumsq (sqi) for the exact l2; per-BLOCK double sumsq partial
// (sqpart) for the bandwidth. Deterministic: fixed-order, no atomics.
__global__ void k_conv(const float* __restrict__ src, const float* __restrict__ tgt,
                       signed char* __restrict__ bfall, int* __restrict__ sqi,
                       double* __restrict__ sqpart, float* __restrict__ cspart) {
    __shared__ float colp[4][NCOLS];
    __shared__ double dred[4];
    int t = threadIdx.x, w = t >> 6, l = t & 63;
    int r0 = blockIdx.x * 32;
    float c0x=0.f,c0y=0.f,c0z=0.f,c0w=0.f, c1x=0.f,c1y=0.f,c1z=0.f,c1w=0.f;
    double facc = 0.0;
    #pragma unroll
    for (int r = 0; r < 8; ++r) {
        int row = r0 + w * 8 + r;
        const float* base = (row < BHALF) ? (src + (size_t)row * NCOLS)
                                          : (tgt + (size_t)(row - BHALF) * NCOLS);
        float4 a = ((const float4*)base)[2 * l];
        float4 b = ((const float4*)base)[2 * l + 1];
        int q0 = (int)rintf(fminf(fmaxf(a.x * QS, -127.f), 127.f));
        int q1 = (int)rintf(fminf(fmaxf(a.y * QS, -127.f), 127.f));
        int q2 = (int)rintf(fminf(fmaxf(a.z * QS, -127.f), 127.f));
        int q3 = (int)rintf(fminf(fmaxf(a.w * QS, -127.f), 127.f));
        int q4 = (int)rintf(fminf(fmaxf(b.x * QS, -127.f), 127.f));
        int q5 = (int)rintf(fminf(fmaxf(b.y * QS, -127.f), 127.f));
        int q6 = (int)rintf(fminf(fmaxf(b.z * QS, -127.f), 127.f));
        int q7 = (int)rintf(fminf(fmaxf(b.w * QS, -127.f), 127.f));
        i8x8 v8;
        v8[0]=(signed char)q0; v8[1]=(signed char)q1; v8[2]=(signed char)q2; v8[3]=(signed char)q3;
        v8[4]=(signed char)q4; v8[5]=(signed char)q5; v8[6]=(signed char)q6; v8[7]=(signed char)q7;
        *(i8x8*)(bfall + (size_t)row * NCOLS + l * 8) = v8;
        float s = a.x*a.x + a.y*a.y + a.z*a.z + a.w*a.w
                + b.x*b.x + b.y*b.y + b.z*b.z + b.w*b.w;
        facc += (double)s;
        int si = q0*q0 + q1*q1 + q2*q2 + q3*q3 + q4*q4 + q5*q5 + q6*q6 + q7*q7;
        #pragma unroll
        for (int o = 32; o > 0; o >>= 1) si += __shfl_down(si, o);
        if (l == 0) sqi[row] = si;
        c0x += a.x; c0y += a.y; c0z += a.z; c0w += a.w;
        c1x += b.x; c1y += b.y; c1z += b.z; c1w += b.w;
    }
    #pragma unroll
    for (int o = 32; o > 0; o >>= 1) facc += __shfl_down(facc, o);
    if (l == 0) dred[w] = facc;
    colp[w][l*8+0] = c0x; colp[w][l*8+1] = c0y; colp[w][l*8+2] = c0z; colp[w][l*8+3] = c0w;
    colp[w][l*8+4] = c1x; colp[w][l*8+5] = c1y; colp[w][l*8+6] = c1z; colp[w][l*8+7] = c1w;
    __syncthreads();
    if (t == 0) sqpart[blockIdx.x] = (dred[0] + dred[1]) + (dred[2] + dred[3]);
    float s0 = colp[0][t] + colp[1][t] + colp[2][t] + colp[3][t];
    float s1 = colp[0][t+256] + colp[1][t+256] + colp[2][t+256] + colp[3][t+256];
    cspart[(size_t)blockIdx.x * NCOLS + t]       = s0;
    cspart[(size_t)blockIdx.x * NCOLS + t + 256] = s1;
}

// ---------- coalesced column reduction: 8 blocks x 256 threads ----------
__global__ void k_red(const float* __restrict__ cspart, double* __restrict__ colsq) {
    __shared__ double lred[4][64];
    int b = blockIdx.x, t = threadIdx.x;
    int c = b * 64 + (t & 63), q = t >> 6;
    double a = 0.0;
    #pragma unroll 4
    for (int p = q * 64; p < q * 64 + 64; ++p)
        a += (double)cspart[(size_t)p * NCOLS + c];
    lred[q][t & 63] = a;
    __syncthreads();
    if (t < 64) {
        double s = (lred[0][t] + lred[1][t]) + (lred[2][t] + lred[3][t]);
        colsq[b * 64 + t] = s * s;
    }
}

// bandwidth from analytic sum(l2) = 2n*T - 2*||colsum||^2 ; store log2(e)/bw_k.
__global__ void k_bw(const double* __restrict__ sqpart, const double* __restrict__ colsq,
                     float* __restrict__ cvals) {
    __shared__ double red[512];
    int t = threadIdx.x;
    red[t] = (t < CSPART) ? sqpart[t] : 0.0;
    __syncthreads();
    for (int o = 256; o > 0; o >>= 1) { if (t < o) red[t] += red[t + o]; __syncthreads(); }
    double sT = red[0];
    __syncthreads();
    red[t] = colsq[t]; __syncthreads();
    for (int o = 256; o > 0; o >>= 1) { if (t < o) red[t] += red[t + o]; __syncthreads(); }
    if (t == 0) {
        double G = red[0];
        double sum_l2 = 2.0 * (double)NROWS * sT - 2.0 * G;
        double denom = (double)NROWS * (double)NROWS - (double)NROWS;
        double bw = sum_l2 / denom / 4.0;   // KERNEL_MUL^(KERNEL_NUM/2) = 4
        const double L2E = 1.4426950408889634;
        double b = bw;
        #pragma unroll
        for (int k = 0; k < 5; ++k) { cvals[k] = (float)(L2E / b); b *= 2.0; }
    }
}

// ---------- main fused MMD kernel: i8 counted-vmcnt LDS pipeline ----------
// R7-proven structure at half scale (i8: 8 K-steps of 16 KB vs bf16's 16):
// 3 LDS buffers (48 KB), prefetch distance 2, per step {vmcnt(4), raw
// s_barrier, STAGE(kt+2) via global_load_lds, 8 ds_read_b128 + 16
// mfma_i32_16x16x64_i8}. Swizzle ss = slot^((row>>1)&3) on pre-swizzled
// global source + same on reads (R7-verified, 2-way bank aliasing = free).
// R9 hoisting: ssl = lk^((lr>>1)&3) m-independent; kt enters as const imm on
// hoisted pointers. Cuts per-CU TCP/L2 request volume 2x vs the streaming
// kernel (block-shared panels staged once). R24 RNE fp16 epilogue (proven),
// dup-diagonal supertile, closed-form decode, XCD swizzle, deterministic.
__global__ __launch_bounds__(256, 3)
void k_mmd(const signed char* __restrict__ bfall, const int* __restrict__ sqi,
           const float* __restrict__ cvals, double* __restrict__ psum) {
    __shared__ signed char lds[3 * 16384];   // buf b: A at b*16384, B at +8192
    __shared__ float wred[4];

    // T1: XCD-aware bijective swizzle (NBLK = 8*260), closed-form decode
    int bid = blockIdx.x;
    int swz = (bid & 7) * (NBLK / 8) + (bid >> 3);
    int v = NBLK - 1 - swz;
    int k = (int)((sqrtf(8.f * (float)v + 1.f) - 1.f) * 0.5f);
    while ((k + 1) * (k + 2) / 2 <= v) ++k;
    while (k * (k + 1) / 2 > v) --k;
    int I = NT - 1 - k;
    int J = NT - 1 - (v - k * (k + 1) / 2);

    const int t  = threadIdx.x;
    const int w  = t >> 6;       // wave 0..3
    const int l  = t & 63;
    const int lr = l & 15;
    const int lk = l >> 4;

    // supertile: block covers rows I*128..+127 x cols J*128..+127;
    // wave w owns the 64x64 quadrant (wr, wc)
    const int wr = w >> 1, wc = w & 1;
    const int rowA0 = I * 128 + wr * 64, rowB0 = J * 128 + wc * 64;
    const signed char* gA = bfall + (size_t)(I * 128) * NCOLS;
    const signed char* gB = bfall + (size_t)(J * 128) * NCOLS;

    // ---- hoisted staging addresses (kt folds into global ptr as imm) ----
    // A tile = 128 rows x 64 B = 512 chunks of 16B; chunk q: row=q>>2,
    // slot=q&3, src ss = slot^((row>>1)&3). Thread t: chunks t and 256+t
    // (row+64 -> same ss -> +64*NCOLS). B identical.
    const int row0 = t >> 2, ss0 = (t & 3) ^ ((row0 >> 1) & 3);
    const signed char* ga0 = gA + (size_t)row0 * NCOLS + ss0 * 16;
    const signed char* gb0 = gB + (size_t)row0 * NCOLS + ss0 * 16;
    signed char* dA = lds + t * 16;          // chunk t; chunk 256+t at +4096
    signed char* dB = lds + 8192 + t * 16;

    // ---- hoisted compute addresses (bsel/m/n enter as const imm) ----
    const int ssl = lk ^ ((lr >> 1) & 3);
    const signed char* pA = lds + (wr * 64 + lr) * 64 + ssl * 16;
    const signed char* pB = lds + 8192 + (wc * 64 + lr) * 64 + ssl * 16;

    #define STAGE(bsel, kt)                                                        \
        __builtin_amdgcn_global_load_lds((guint*)(ga0 + (kt) * 64),                \
            (luint*)(dA + (bsel) * 16384), 16, 0, 0);                              \
        __builtin_amdgcn_global_load_lds((guint*)(ga0 + 64 * NCOLS + (kt) * 64),   \
            (luint*)(dA + (bsel) * 16384 + 4096), 16, 0, 0);                       \
        __builtin_amdgcn_global_load_lds((guint*)(gb0 + (kt) * 64),                \
            (luint*)(dB + (bsel) * 16384), 16, 0, 0);                              \
        __builtin_amdgcn_global_load_lds((guint*)(gb0 + 64 * NCOLS + (kt) * 64),   \
            (luint*)(dB + (bsel) * 16384 + 4096), 16, 0, 0);

    #define COMPUTE(bsel)                                                          \
        {                                                                          \
            i32x4 af[4], bf[4];                                                    \
            _Pragma("unroll")                                                      \
            for (int m = 0; m < 4; ++m)                                            \
                af[m] = *(const i32x4*)(pA + (bsel) * 16384 + m * 1024);           \
            _Pragma("unroll")                                                      \
            for (int n = 0; n < 4; ++n)                                            \
                bf[n] = *(const i32x4*)(pB + (bsel) * 16384 + n * 1024);           \
            _Pragma("unroll")                                                      \
            for (int m = 0; m < 4; ++m)                                            \
                _Pragma("unroll")                                                  \
                for (int n = 0; n < 4; ++n)                                        \
                    acc[m][n] = __builtin_amdgcn_mfma_i32_16x16x64_i8(             \
                        af[m], bf[n], acc[m][n], 0, 0, 0);                         \
        }

    // step kt: wait own stage(kt) landed (kt+1 stays in flight); barrier
    // certifies all waves' stage(kt) landed + buffer (kt+2)%3 free; prefetch
    // kt+2; compute kt. (R7-proven schedule.)
    #define STEP(kt, vm)                                                           \
        asm volatile("s_waitcnt vmcnt(" #vm ")" ::: "memory");                     \
        __builtin_amdgcn_s_barrier();                                              \
        asm volatile("" ::: "memory");                                             \
        if ((kt) + 2 < 8) { STAGE(((kt) + 2) % 3, (kt) + 2) }                      \
        COMPUTE((kt) % 3)

    i32x4 acc[4][4] = {};

    STAGE(0, 0)
    STAGE(1, 1)        // 8 loads in flight

    STEP(0, 4) STEP(1, 4) STEP(2, 4) STEP(3, 4)
    STEP(4, 4) STEP(5, 4) STEP(6, 4) STEP(7, 0)

    #undef STAGE
    #undef COMPUTE
    #undef STEP

    // ---------- epilogue (R24-proven RNE fp16 path) ----------
    i32x4 sqa[4];
    #pragma unroll
    for (int m = 0; m < 4; ++m)
        sqa[m] = *(const i32x4*)&sqi[rowA0 + m * 16 + lk * 4];
    int sqb[4];
    #pragma unroll
    for (int n = 0; n < 4; ++n)
        sqb[n] = sqi[rowB0 + n * 16 + lr];
    const float c4i = cvals[4] * INV_S2;   // fold 1/s^2 into the exp constant
    const float c2  = 2.f * c4i;
    f32x4 sqaf[4];
    #pragma unroll
    for (int m = 0; m < 4; ++m)
        #pragma unroll
        for (int r = 0; r < 4; ++r)
            sqaf[m][r] = c4i * (float)sqa[m][r];
    float sqbf[4];
    #pragma unroll
    for (int n = 0; n < 4; ++n)
        sqbf[n] = c4i * (float)sqb[n];

    const bool dsup = (I == J);
    const bool elem = dsup && (wr == wc);            // diagonal quadrants
    const float wb  = (dsup || elem) ? 1.f : 2.f;    // off-diag tiles weight 2
    const float sgn = ((rowA0 < BHALF) == (rowB0 < BHALF)) ? 1.f : -1.f;
    // NOTE: dsup non-elem quadrants (wr!=wc) are the two symmetric off-diag
    // 64-tiles of a diagonal super -- each computed once, weight 2 total, but
    // both quadrants present (01 and 10) -> weight 1 each. wb=1 for them.
    float local = 0.f;
    if (elem) {
        #pragma unroll
        for (int m = 0; m < 4; ++m)
            #pragma unroll
            for (int n = 0; n < 4; ++n)
                #pragma unroll
                for (int r = 0; r < 4; ++r) {
                    float x  = __builtin_amdgcn_exp2f(
                        fmaf((float)acc[m][n][r], c2, -(sqaf[m][r] + sqbf[n])));
                    float x2 = x * x;
                    float x4 = x2 * x2;
                    float x8 = x4 * x4;
                    float e  = fmaf(x8, x8, x8) + ((x + x2) + x4);
                    int gi = rowA0 + m * 16 + lk * 4 + r;
                    int gj = rowB0 + n * 16 + lr;
                    float wgt = (gj > gi) ? 2.f : ((gj == gi) ? 1.f : 0.f);
                    local += wgt * e;
                }
    } else {
        const h16x2 ones = {(__fp16)1.f, (__fp16)1.f};
        #pragma unroll
        for (int m = 0; m < 4; ++m)
            #pragma unroll
            for (int n = 0; n < 4; ++n)
                #pragma unroll
                for (int rp = 0; rp < 2; ++rp) {
                    float x0 = __builtin_amdgcn_exp2f(
                        fmaf((float)acc[m][n][2*rp],     c2, -(sqaf[m][2*rp]     + sqbf[n])));
                    float x1 = __builtin_amdgcn_exp2f(
                        fmaf((float)acc[m][n][2*rp + 1], c2, -(sqaf[m][2*rp + 1] + sqbf[n])));
                    h16x2 x  = {(__fp16)x0, (__fp16)x1};   // RNE converts
                    h16x2 x2 = x * x;
                    h16x2 x4 = x2 * x2;
                    h16x2 x8 = x4 * x4;
                    h16x2 e2 = ((x + x2) + (x4 + x8)) + x8 * x8;
#if __has_builtin(__builtin_amdgcn_fdot2)
                    local = __builtin_amdgcn_fdot2(e2, ones, local, false);
#else
                    local += (float)e2[0] + (float)e2[1];
#endif
                }
        // dsup off-diag quadrants: both (01),(10) computed -> weight 1 each,
        // sgn always +1 inside a diagonal super. Non-dsup: weight 2, sgn.
        local *= wb * sgn;
    }

    #pragma unroll
    for (int o = 32; o > 0; o >>= 1) local += __shfl_down(local, o);
    if (l == 0) wred[w] = local;
    __syncthreads();
    if (t == 0) {
        psum[blockIdx.x] = (double)((wred[0] + wred[1]) + (wred[2] + wred[3]));
    }
}

// fixed-order final reduction over NBLK partials -> loss
__global__ void k_final(const double* __restrict__ psum, float* __restrict__ out) {
    __shared__ double red[512];
    int t = threadIdx.x;
    double a = 0.0;
    #pragma unroll
    for (int i = t; i < NBLK; i += 512) a += psum[i];
    red[t] = a; __syncthreads();
    for (int o = 256; o > 0; o >>= 1) { if (t < o) red[t] += red[t + o]; __syncthreads(); }
    if (t == 0) out[0] = (float)(red[0] * (1.0 / ((double)BHALF * (double)BHALF)));
}

// ---------- launch ----------
extern "C" void kernel_launch(void* const* d_in, const int* in_sizes, int n_in,
                              void* d_out, int out_size, void* d_ws, size_t ws_size,
                              hipStream_t stream) {
    (void)in_sizes; (void)n_in; (void)out_size; (void)ws_size;
    const float* src = (const float*)d_in[0];
    const float* tgt = (const float*)d_in[1];
    float* out = (float*)d_out;
    char* ws = (char*)d_ws;
    // layout (16B-aligned; every consumed word is rewritten each call):
    signed char* bfall = (signed char*)(ws);          // 4194304 B (row-major i8)
    int*    sqi    = (int*)   (ws + 4194304);         // 32768 B
    float*  cspart = (float*) (ws + 4227072);         // 524288 B
    float*  cvals  = (float*) (ws + 4751360);         // 20 B (pad 32)
    double* colsq  = (double*)(ws + 4751392);         // 4096 B
    double* sqpart = (double*)(ws + 4755488);         // 2048 B
    double* psum   = (double*)(ws + 4757536);         // 2080*8 = 16640 B

    k_conv  <<<CSPART, 256, 0, stream>>>(src, tgt, bfall, sqi, sqpart, cspart);
    k_red   <<<8, 256, 0, stream>>>(cspart, colsq);
    k_bw    <<<1, 512, 0, stream>>>(sqpart, colsq, cvals);
    k_mmd   <<<NBLK, 256, 0, stream>>>(bfall, sqi, cvals, psum);
    k_final <<<1, 512, 0, stream>>>(psum, out);
}